// Round 10
// baseline (287.418 us; speedup 1.0000x reference)
//
#include <hip/hip_runtime.h>
#include <hip/hip_bf16.h>

// MHA forward, MI355X gfx950.
// B=2, S=2048, D=1024, H=16, DK=64.
// d_out: [out (2,2048,1024) f32][attn_weights (2,16,2048,2048) f32]
//
// Frag-major bf16 (one MFMA A/B fragment = 16x32 = 1KB, lane l's 16B at
// offset l*16). 5 dispatches:
//   memset(flag) -> prologue(converts+mask) -> proj_qkv(z=0..2) -> attn -> proj_o
// ws: A0 qbf->ctxf | A1 kbf | A2 vbf | A3 qhf | Wb wqf..wof | flag
// khf/vhf live in d_out's `out` region (scratch until proj_o overwrites it).
//
// attn v7: 1024-thr blocks (16 waves), one block = (b,h) x 32 q-rows as TWO
// 16-row groups. Each wave owns a 128-col k-range and computes both groups'
// scores from the SAME K/V fragments -> K/V L2 traffic halves vs v4 while
// per-wave register state stays ~v4 (sA[8]+sB[8] == old sacc[16]).
// Journal: R6/R7 (2 tiles per WAVE) spilled — 2 tiles per BLOCK across 2x
// waves is the register-safe form.

#define DEVI __device__ __forceinline__

typedef short bf16x8 __attribute__((ext_vector_type(8)));
typedef float f32x4  __attribute__((ext_vector_type(4)));
typedef unsigned short u16x4 __attribute__((ext_vector_type(4)));
typedef unsigned int u32x4 __attribute__((ext_vector_type(4)));

static constexpr int S = 2048;
static constexpr int DK = 64;
static constexpr size_t A_ELEMS = 4194304;   // 4096*1024
static constexpr size_t W_ELEMS = 1048576;   // 1024*1024
static constexpr size_t BH_ELEMS = 131072;   // 2048*64

DEVI unsigned short f2bf(float f) {
  unsigned u = __float_as_uint(f);
  unsigned r = u + 0x7fffu + ((u >> 16) & 1u);  // RNE
  return (unsigned short)(r >> 16);
}

// ---------------------------------------------------------------- prologue
__global__ __launch_bounds__(256) void prologue_kernel(
    const float* __restrict__ q, const float* __restrict__ k,
    const float* __restrict__ v, const float* __restrict__ w_q,
    const float* __restrict__ w_k, const float* __restrict__ w_v,
    const float* __restrict__ w_o, const int* __restrict__ mask,
    unsigned short* __restrict__ Abase, unsigned short* __restrict__ Wbase,
    int* __restrict__ flag) {
  const int bid = blockIdx.x;
  if (bid < 8192) {
    const float* src;
    unsigned short* dst;
    int t;
    if (bid < 6144) {
      const int z = bid >> 11;
      src = (z == 0) ? q : (z == 1) ? k : v;
      dst = Abase + (size_t)z * A_ELEMS;
      t = (bid & 2047) * 256 + threadIdx.x;   // 0..524287 over [4096][1024]
    } else {
      const int rz = bid - 6144;
      const int z = rz >> 9;
      src = (z == 0) ? w_q : (z == 1) ? w_k : (z == 2) ? w_v : w_o;
      dst = Wbase + (size_t)z * W_ELEMS;
      t = (rz & 511) * 256 + threadIdx.x;     // 0..131071 over [1024][1024]
    }
    const int r = t >> 7, i0 = (t & 127) << 3;
    const float4* s4 = (const float4*)(src + (size_t)r * 1024 + i0);
    float4 a = s4[0], b = s4[1];
    bf16x8 pk;
    pk[0] = (short)f2bf(a.x); pk[1] = (short)f2bf(a.y);
    pk[2] = (short)f2bf(a.z); pk[3] = (short)f2bf(a.w);
    pk[4] = (short)f2bf(b.x); pk[5] = (short)f2bf(b.y);
    pk[6] = (short)f2bf(b.z); pk[7] = (short)f2bf(b.w);
    size_t addr = ((size_t)((r >> 4) * 32 + (i0 >> 5)) << 9) +
                  (((i0 >> 3) & 3) << 7) + ((r & 15) << 3);
    *(bf16x8*)(dst + addr) = pk;
  } else {
    const int mb = bid - 8192;
    const int4* m4 = (const int4*)mask;
    int acc = ~0;
    for (int i = mb * 256 + threadIdx.x; i < S * S / 4; i += 1024 * 256) {
      int4 vv = m4[i];
      acc &= vv.x & vv.y & vv.z & vv.w;
    }
    if (acc == 0) atomicAnd(flag, 0);
  }
}

// ---------------------------------------------------------------- merged QKV projection
__global__ __launch_bounds__(256) void proj_qkv(
    const unsigned short* __restrict__ Abase, const unsigned short* __restrict__ Wbase,
    const float* __restrict__ b_q, const float* __restrict__ b_k,
    const float* __restrict__ b_v, unsigned short* __restrict__ qhf,
    unsigned short* __restrict__ khf, unsigned short* __restrict__ vhf,
    float qscale) {
  const int z = blockIdx.z;
  const unsigned short* Af = Abase + (size_t)z * A_ELEMS;
  const unsigned short* Wf = Wbase + (size_t)z * W_ELEMS;
  const float* bias = (z == 0) ? b_q : (z == 1) ? b_k : b_v;
  unsigned short* outp = (z == 0) ? qhf : (z == 1) ? khf : vhf;
  const float scale = (z == 0) ? qscale : 1.0f;

  const int t = threadIdx.x, l = t & 63, w = t >> 6;
  const int wr = w >> 1, wc = w & 1;
  const int bx = blockIdx.x, by = blockIdx.y;

  const unsigned short* a0 = Af + (((size_t)(bx * 8 + wr * 4) * 32) << 9) + l * 8;
  const unsigned short* b0 = Wf + (((size_t)(by * 4 + wc * 2) * 32) << 9) + l * 8;

  f32x4 acc[4][2];
#pragma unroll
  for (int m = 0; m < 4; ++m)
#pragma unroll
    for (int n = 0; n < 2; ++n) acc[m][n] = {0.f, 0.f, 0.f, 0.f};

#pragma unroll 4
  for (int c = 0; c < 32; ++c) {
    bf16x8 af[4], bfr[2];
#pragma unroll
    for (int m = 0; m < 4; ++m)
      af[m] = *(const bf16x8*)(a0 + (((size_t)(m * 32 + c)) << 9));
#pragma unroll
    for (int n = 0; n < 2; ++n)
      bfr[n] = *(const bf16x8*)(b0 + (((size_t)(n * 32 + c)) << 9));
#pragma unroll
    for (int n = 0; n < 2; ++n)
#pragma unroll
      for (int m = 0; m < 4; ++m)
        acc[m][n] = __builtin_amdgcn_mfma_f32_16x16x32_bf16(af[m], bfr[n], acc[m][n], 0, 0, 0);
  }

  const int l4 = (l >> 4) << 2, cl = l & 15;
#pragma unroll
  for (int n = 0; n < 2; ++n) {
    const int gc = by * 64 + wc * 32 + n * 16 + cl;
    const float bi = bias[gc];
#pragma unroll
    for (int m = 0; m < 4; ++m) {
      const int gr0 = bx * 128 + wr * 64 + m * 16 + l4;
      const int b = gr0 >> 11, s0 = gr0 & 2047, h = gc >> 6, d = gc & 63;
      const size_t base = (size_t)(b * 16 + h) * BH_ELEMS;
      if (z != 2) {
#pragma unroll
        for (int j = 0; j < 4; ++j) {
          const int s = s0 + j;
          size_t addr = base + ((size_t)((s >> 4) * 2 + (d >> 5)) << 9) +
                        (((d >> 3) & 3) << 7) + ((s & 15) << 3) + (d & 7);
          outp[addr] = f2bf((acc[m][n][j] + bi) * scale);
        }
      } else {
        size_t addr = base + ((size_t)((s0 >> 5) * 4 + (d >> 4)) << 9) +
                      (((s0 >> 3) & 3) << 7) + ((d & 15) << 3) + (s0 & 7);
        u16x4 pk;
#pragma unroll
        for (int j = 0; j < 4; ++j) pk[j] = f2bf(acc[m][n][j] + bi);
        *(u16x4*)(outp + addr) = pk;
      }
    }
  }
}

// ---------------------------------------------------------------- O projection
__global__ __launch_bounds__(256) void proj_o(const unsigned short* __restrict__ Af,
                                              const unsigned short* __restrict__ Wf,
                                              const float* __restrict__ bias,
                                              float* __restrict__ outp) {
  const int t = threadIdx.x, l = t & 63, w = t >> 6;
  const int wr = w >> 1, wc = w & 1;
  const int bx = blockIdx.x, by = blockIdx.y;

  const unsigned short* a0 = Af + (((size_t)(bx * 8 + wr * 4) * 32) << 9) + l * 8;
  const unsigned short* b0 = Wf + (((size_t)(by * 4 + wc * 2) * 32) << 9) + l * 8;

  f32x4 acc[4][2];
#pragma unroll
  for (int m = 0; m < 4; ++m)
#pragma unroll
    for (int n = 0; n < 2; ++n) acc[m][n] = {0.f, 0.f, 0.f, 0.f};

#pragma unroll 4
  for (int c = 0; c < 32; ++c) {
    bf16x8 af[4], bfr[2];
#pragma unroll
    for (int m = 0; m < 4; ++m)
      af[m] = *(const bf16x8*)(a0 + (((size_t)(m * 32 + c)) << 9));
#pragma unroll
    for (int n = 0; n < 2; ++n)
      bfr[n] = *(const bf16x8*)(b0 + (((size_t)(n * 32 + c)) << 9));
#pragma unroll
    for (int n = 0; n < 2; ++n)
#pragma unroll
      for (int m = 0; m < 4; ++m)
        acc[m][n] = __builtin_amdgcn_mfma_f32_16x16x32_bf16(af[m], bfr[n], acc[m][n], 0, 0, 0);
  }

  const int l4 = (l >> 4) << 2, cl = l & 15;
#pragma unroll
  for (int n = 0; n < 2; ++n) {
    const int gc = by * 64 + wc * 32 + n * 16 + cl;
    const float bi = bias[gc];
#pragma unroll
    for (int m = 0; m < 4; ++m) {
      const int gr0 = bx * 128 + wr * 64 + m * 16 + l4;
#pragma unroll
      for (int j = 0; j < 4; ++j)
        outp[(size_t)(gr0 + j) * 1024 + gc] = acc[m][n][j] + bi;
    }
  }
}

// ---------------------------------------------------------------- attention v7
// 1024 threads / 16 waves; one block = one (b,h) x 32 q-rows (two 16-row
// groups A/B). Wave w16 owns k-range [w16*128, w16*128+128) and computes
// BOTH groups from the same K/V frags. Swapped QK^T: lane owns row q=l&15,
// k = w16*128 + ct*16 + 4*(l>>4)+j.
__global__ __launch_bounds__(1024, 4) void attn_v7(const unsigned short* __restrict__ Qf,
                                                   const unsigned short* __restrict__ Kf,
                                                   const unsigned short* __restrict__ Vf,
                                                   const int* __restrict__ mask,
                                                   const int* __restrict__ flag,
                                                   float* __restrict__ Pout,
                                                   unsigned short* __restrict__ ctxf) {
  __shared__ float red[16 * 1024];     // 64 KB: ctx reduce (group A then B)
  __shared__ float rredm[2][16][16];   // per-group row-max slots
  __shared__ float rreds[2][16][16];   // per-group row-sum slots

  const int t = threadIdx.x, l = t & 63, w16 = t >> 6;   // w16: 0..15
  const int bid = blockIdx.x;
  const int swz = (bid & 7) * 256 + (bid >> 3);   // bijective: 2048 % 8 == 0
  const int bh = swz >> 6, rt2 = swz & 63;
  const int rtA = rt2 * 2, rtB = rtA + 1;
  const int q0A = rtA * 16, q0B = rtB * 16;
  const int g = l >> 4, q = l & 15;

  const unsigned short* qf = Qf + (size_t)bh * BH_ELEMS + l * 8;
  const unsigned short* kf = Kf + (size_t)bh * BH_ELEMS + l * 8;
  const unsigned short* vf = Vf + (size_t)bh * BH_ELEMS + l * 8;

  const bf16x8 aqA0 = *(const bf16x8*)(qf + ((size_t)(rtA * 2) << 9));
  const bf16x8 aqA1 = *(const bf16x8*)(qf + ((size_t)(rtA * 2 + 1) << 9));
  const bf16x8 aqB0 = *(const bf16x8*)(qf + ((size_t)(rtB * 2) << 9));
  const bf16x8 aqB1 = *(const bf16x8*)(qf + ((size_t)(rtB * 2 + 1) << 9));

  // ---- scores: both groups from the same K frags
  f32x4 sA[8], sB[8];
#pragma unroll
  for (int ct = 0; ct < 8; ++ct) {
    const int gi = w16 * 8 + ct;
    bf16x8 ak0 = *(const bf16x8*)(kf + ((size_t)(gi * 2) << 9));
    bf16x8 ak1 = *(const bf16x8*)(kf + ((size_t)(gi * 2 + 1) << 9));
    f32x4 a = {0.f, 0.f, 0.f, 0.f};
    a = __builtin_amdgcn_mfma_f32_16x16x32_bf16(ak0, aqA0, a, 0, 0, 0);
    a = __builtin_amdgcn_mfma_f32_16x16x32_bf16(ak1, aqA1, a, 0, 0, 0);
    sA[ct] = a;
    f32x4 b = {0.f, 0.f, 0.f, 0.f};
    b = __builtin_amdgcn_mfma_f32_16x16x32_bf16(ak0, aqB0, b, 0, 0, 0);
    b = __builtin_amdgcn_mfma_f32_16x16x32_bf16(ak1, aqB1, b, 0, 0, 0);
    sB[ct] = b;
    if ((ct & 3) == 3) __builtin_amdgcn_sched_barrier(0);
  }

  // ---- mask slow path
  if (*flag == 0) {
#pragma unroll
    for (int ct = 0; ct < 8; ++ct) {
      const int col = w16 * 128 + ct * 16 + g * 4;
#pragma unroll
      for (int j = 0; j < 4; ++j) {
        if (mask[(size_t)(q0A + q) * S + col + j] == 0) sA[ct][j] = -1e9f;
        if (mask[(size_t)(q0B + q) * S + col + j] == 0) sB[ct][j] = -1e9f;
      }
    }
  }

  // ---- softmax (scores pre-scaled by log2e); rows live across 16 waves
  float mA = -1e30f, mB = -1e30f;
#pragma unroll
  for (int ct = 0; ct < 8; ++ct)
#pragma unroll
    for (int j = 0; j < 4; ++j) {
      mA = fmaxf(mA, sA[ct][j]);
      mB = fmaxf(mB, sB[ct][j]);
    }
  mA = fmaxf(mA, __shfl_xor(mA, 16)); mA = fmaxf(mA, __shfl_xor(mA, 32));
  mB = fmaxf(mB, __shfl_xor(mB, 16)); mB = fmaxf(mB, __shfl_xor(mB, 32));
  if (l < 16) { rredm[0][w16][l] = mA; rredm[1][w16][l] = mB; }
  __syncthreads();
  float mmA = rredm[0][0][q], mmB = rredm[1][0][q];
#pragma unroll
  for (int ww = 1; ww < 16; ++ww) {
    mmA = fmaxf(mmA, rredm[0][ww][q]);
    mmB = fmaxf(mmB, rredm[1][ww][q]);
  }

  float zA = 0.f, zB = 0.f;
#pragma unroll
  for (int ct = 0; ct < 8; ++ct)
#pragma unroll
    for (int j = 0; j < 4; ++j) {
      float pA = exp2f(sA[ct][j] - mmA); sA[ct][j] = pA; zA += pA;
      float pB = exp2f(sB[ct][j] - mmB); sB[ct][j] = pB; zB += pB;
    }
  zA += __shfl_xor(zA, 16); zA += __shfl_xor(zA, 32);
  zB += __shfl_xor(zB, 16); zB += __shfl_xor(zB, 32);
  if (l < 16) { rreds[0][w16][l] = zA; rreds[1][w16][l] = zB; }
  __syncthreads();
  float zzA = rreds[0][0][q], zzB = rreds[1][0][q];
#pragma unroll
  for (int ww = 1; ww < 16; ++ww) {
    zzA += rreds[0][ww][q];
    zzB += rreds[1][ww][q];
  }
  const float invA = 1.0f / zzA, invB = 1.0f / zzB;

  // ---- normalize + vectorized nontemporal P store (row-contiguous)
  {
    float* prowA = Pout + ((size_t)bh * S + q0A + q) * S + w16 * 128 + g * 4;
    float* prowB = Pout + ((size_t)bh * S + q0B + q) * S + w16 * 128 + g * 4;
#pragma unroll
    for (int ct = 0; ct < 8; ++ct) {
      f32x4 pnA = sA[ct] * invA; sA[ct] = pnA;
      __builtin_nontemporal_store(pnA, (f32x4*)(prowA + ct * 16));
      f32x4 pnB = sB[ct] * invB; sB[ct] = pnB;
      __builtin_nontemporal_store(pnB, (f32x4*)(prowB + ct * 16));
    }
  }

  // ---- pack P -> bf16 A-frags in-register (butterfly), both groups
  u32x4 paA[4], paB[4];
#pragma unroll
  for (int grp = 0; grp < 2; ++grp) {
    f32x4* sv = (grp == 0) ? sA : sB;
    u32x4* pa = (grp == 0) ? paA : paB;
#pragma unroll
    for (int ks = 0; ks < 4; ++ks) {
      const int t0 = ks * 2, t1 = t0 + 1;
      unsigned Xa, Xb, Ya, Yb;
      asm("v_cvt_pk_bf16_f32 %0, %1, %2" : "=v"(Xa) : "v"(sv[t0][0]), "v"(sv[t0][1]));
      asm("v_cvt_pk_bf16_f32 %0, %1, %2" : "=v"(Xb) : "v"(sv[t0][2]), "v"(sv[t0][3]));
      asm("v_cvt_pk_bf16_f32 %0, %1, %2" : "=v"(Ya) : "v"(sv[t1][0]), "v"(sv[t1][1]));
      asm("v_cvt_pk_bf16_f32 %0, %1, %2" : "=v"(Yb) : "v"(sv[t1][2]), "v"(sv[t1][3]));
      const bool lo2 = (g < 2);
      unsigned sel_a = lo2 ? Ya : Xa, sel_b = lo2 ? Yb : Xb;
      unsigned kept_a = lo2 ? Xa : Ya, kept_b = lo2 ? Xb : Yb;
      unsigned r1_a = (unsigned)__shfl_xor((int)sel_a, 32);
      unsigned r1_b = (unsigned)__shfl_xor((int)sel_b, 32);
      const bool mid = (g == 1) || (g == 2);
      unsigned s2_a = mid ? kept_a : r1_a;
      unsigned s2_b = mid ? kept_b : r1_b;
      unsigned r2_a = (unsigned)__shfl_xor((int)s2_a, 16);
      unsigned r2_b = (unsigned)__shfl_xor((int)s2_b, 16);
      u32x4 fr;
      fr[0] = (g == 0) ? kept_a : ((g == 2) ? r1_a : r2_a);
      fr[1] = (g == 0) ? kept_b : ((g == 2) ? r1_b : r2_b);
      fr[2] = (g == 3) ? kept_a : ((g == 1) ? r1_a : r2_a);
      fr[3] = (g == 3) ? kept_b : ((g == 1) ? r1_b : r2_b);
      pa[ks] = fr;
    }
  }

  // ---- PV: both groups from the same V frags
  f32x4 paccA[4], paccB[4];
#pragma unroll
  for (int n = 0; n < 4; ++n) {
    paccA[n] = {0.f, 0.f, 0.f, 0.f};
    paccB[n] = {0.f, 0.f, 0.f, 0.f};
  }

  __builtin_amdgcn_s_setprio(1);
#pragma unroll
  for (int ks = 0; ks < 4; ++ks) {
    const bf16x8 apA = __builtin_bit_cast(bf16x8, paA[ks]);
    const bf16x8 apB = __builtin_bit_cast(bf16x8, paB[ks]);
    const int kbi = w16 * 4 + ks;
#pragma unroll
    for (int n = 0; n < 4; ++n) {
      bf16x8 bv = *(const bf16x8*)(vf + ((size_t)(kbi * 4 + n) << 9));
      paccA[n] = __builtin_amdgcn_mfma_f32_16x16x32_bf16(apA, bv, paccA[n], 0, 0, 0);
      paccB[n] = __builtin_amdgcn_mfma_f32_16x16x32_bf16(apB, bv, paccB[n], 0, 0, 0);
    }
  }
  __builtin_amdgcn_s_setprio(0);

  // ---- ctx reduce over 16 k-slices: group A then group B through red[]
  const int b = bh >> 4, h = bh & 15;
#pragma unroll
  for (int n = 0; n < 4; ++n)
#pragma unroll
    for (int j = 0; j < 4; ++j)
      red[w16 * 1024 + (g * 4 + j) * 64 + n * 16 + q] = paccA[n][j];
  __syncthreads();
  {
    float s = red[t];
#pragma unroll
    for (int ww = 1; ww < 16; ++ww) s += red[ww * 1024 + t];
    int qrow = t >> 6, d = t & 63;
    size_t addr = ((size_t)((b * 128 + rtA) * 32 + h * 2 + (d >> 5)) << 9) +
                  (((d >> 3) & 3) << 7) + (qrow << 3) + (d & 7);
    ctxf[addr] = f2bf(s);
  }
  __syncthreads();
#pragma unroll
  for (int n = 0; n < 4; ++n)
#pragma unroll
    for (int j = 0; j < 4; ++j)
      red[w16 * 1024 + (g * 4 + j) * 64 + n * 16 + q] = paccB[n][j];
  __syncthreads();
  {
    float s = red[t];
#pragma unroll
    for (int ww = 1; ww < 16; ++ww) s += red[ww * 1024 + t];
    int qrow = t >> 6, d = t & 63;
    size_t addr = ((size_t)((b * 128 + rtB) * 32 + h * 2 + (d >> 5)) << 9) +
                  (((d >> 3) & 3) << 7) + (qrow << 3) + (d & 7);
    ctxf[addr] = f2bf(s);
  }
}

// ---------------------------------------------------------------- launch
extern "C" void kernel_launch(void* const* d_in, const int* in_sizes, int n_in,
                              void* d_out, int out_size, void* d_ws, size_t ws_size,
                              hipStream_t stream) {
  const float* q = (const float*)d_in[0];
  const float* k = (const float*)d_in[1];
  const float* v = (const float*)d_in[2];
  const int* mask = (const int*)d_in[3];
  const float* w_q = (const float*)d_in[4];
  const float* b_q = (const float*)d_in[5];
  const float* w_k = (const float*)d_in[6];
  const float* b_k = (const float*)d_in[7];
  const float* w_v = (const float*)d_in[8];
  const float* b_v = (const float*)d_in[9];
  const float* w_o = (const float*)d_in[10];
  const float* b_o = (const float*)d_in[11];

  unsigned short* wsu = (unsigned short*)d_ws;
  unsigned short* A0 = wsu + 0 * A_ELEMS;  // qbf -> ctxf
  unsigned short* Wb = wsu + 4 * A_ELEMS;  // wqf|wkf|wvf|wof
  unsigned short* A3 = wsu + 3 * A_ELEMS;  // qhf
  unsigned short* wof = Wb + 3 * W_ELEMS;
  int* flag = (int*)(Wb + 4 * W_ELEMS);

  float* out_f = (float*)d_out;                  // [4096][1024] f32
  float* attnW = out_f + (size_t)4096 * 1024;    // [2][16][2048][2048] f32
  // khf/vhf scratch inside the (not-yet-final) `out` region:
  unsigned short* khf = (unsigned short*)d_out;          // 8.39 MB
  unsigned short* vhf = khf + A_ELEMS;                   // 8.39 MB

  (void)hipMemsetAsync(flag, 0xFF, 4, stream);  // flag!=0 default; mask ANDs to 0
  prologue_kernel<<<9216, 256, 0, stream>>>(q, k, v, w_q, w_k, w_v, w_o, mask,
                                            A0, Wb, flag);

  // qscale folds 1/sqrt(64) AND log2(e) (softmax done in exp2 domain).
  const float qscale = 0.125f * 1.4426950408889634f;
  proj_qkv<<<dim3(32, 16, 3), 256, 0, stream>>>(A0, Wb, b_q, b_k, b_v,
                                                A3, khf, vhf, qscale);

  attn_v7<<<2048, 1024, 0, stream>>>(A3, khf, vhf, mask, flag, attnW, A0);

  proj_o<<<dim3(32, 16), 256, 0, stream>>>(A0, wof, b_o, out_f);
}

// Round 11
// 262.886 us; speedup vs baseline: 1.0933x; 1.0933x over previous
//
#include <hip/hip_runtime.h>
#include <hip/hip_bf16.h>

// MHA forward, MI355X gfx950.  == R5 configuration (measured best: 263.5us) ==
// B=2, S=2048, D=1024, H=16, DK=64.
// d_out: [out (2,2048,1024) f32][attn_weights (2,16,2048,2048) f32]
//
// Frag-major bf16 (one MFMA A/B fragment = 16x32 = 1KB, lane l's 16B at
// offset l*16). 5 dispatches:
//   memset(flag) -> prologue(converts+mask) -> proj_qkv(z=0..2) -> attn -> proj_o
// ws: A0 qbf->ctxf | A1 kbf | A2 vbf | A3 qhf | Wb wqf..wof | flag
// khf/vhf live in d_out's `out` region (scratch until proj_o overwrites it).
//
// Journal of refuted directions (do not revisit):
//  - 2 q-tiles per WAVE (R6 rolled/R7 unrolled): sacc doubles -> VGPR spill.
//  - 2 q-tiles per BLOCK via 1024-thr blocks (R10): 1 block/CU kills overlap.
//  - NT loads in prologue (R9): neutral-to-negative.
//  - raw lgkmcnt-only barriers + "memory" clobbers (R6): regalloc collapse.
//  - per-ks sched_barrier inside PV (R3): blocks V-load hoisting.

#define DEVI __device__ __forceinline__

typedef short bf16x8 __attribute__((ext_vector_type(8)));
typedef float f32x4  __attribute__((ext_vector_type(4)));
typedef unsigned short u16x4 __attribute__((ext_vector_type(4)));
typedef unsigned int u32x4 __attribute__((ext_vector_type(4)));

static constexpr int S = 2048;
static constexpr int DK = 64;
static constexpr size_t A_ELEMS = 4194304;   // 4096*1024
static constexpr size_t W_ELEMS = 1048576;   // 1024*1024
static constexpr size_t BH_ELEMS = 131072;   // 2048*64

DEVI unsigned short f2bf(float f) {
  unsigned u = __float_as_uint(f);
  unsigned r = u + 0x7fffu + ((u >> 16) & 1u);  // RNE
  return (unsigned short)(r >> 16);
}

// ---------------------------------------------------------------- prologue
__global__ __launch_bounds__(256) void prologue_kernel(
    const float* __restrict__ q, const float* __restrict__ k,
    const float* __restrict__ v, const float* __restrict__ w_q,
    const float* __restrict__ w_k, const float* __restrict__ w_v,
    const float* __restrict__ w_o, const int* __restrict__ mask,
    unsigned short* __restrict__ Abase, unsigned short* __restrict__ Wbase,
    int* __restrict__ flag) {
  const int bid = blockIdx.x;
  if (bid < 8192) {
    const float* src;
    unsigned short* dst;
    int t;
    if (bid < 6144) {
      const int z = bid >> 11;
      src = (z == 0) ? q : (z == 1) ? k : v;
      dst = Abase + (size_t)z * A_ELEMS;
      t = (bid & 2047) * 256 + threadIdx.x;   // 0..524287 over [4096][1024]
    } else {
      const int rz = bid - 6144;
      const int z = rz >> 9;
      src = (z == 0) ? w_q : (z == 1) ? w_k : (z == 2) ? w_v : w_o;
      dst = Wbase + (size_t)z * W_ELEMS;
      t = (rz & 511) * 256 + threadIdx.x;     // 0..131071 over [1024][1024]
    }
    const int r = t >> 7, i0 = (t & 127) << 3;
    const float4* s4 = (const float4*)(src + (size_t)r * 1024 + i0);
    float4 a = s4[0], b = s4[1];
    bf16x8 pk;
    pk[0] = (short)f2bf(a.x); pk[1] = (short)f2bf(a.y);
    pk[2] = (short)f2bf(a.z); pk[3] = (short)f2bf(a.w);
    pk[4] = (short)f2bf(b.x); pk[5] = (short)f2bf(b.y);
    pk[6] = (short)f2bf(b.z); pk[7] = (short)f2bf(b.w);
    size_t addr = ((size_t)((r >> 4) * 32 + (i0 >> 5)) << 9) +
                  (((i0 >> 3) & 3) << 7) + ((r & 15) << 3);
    *(bf16x8*)(dst + addr) = pk;
  } else {
    const int mb = bid - 8192;
    const int4* m4 = (const int4*)mask;
    int acc = ~0;
    for (int i = mb * 256 + threadIdx.x; i < S * S / 4; i += 1024 * 256) {
      int4 vv = m4[i];
      acc &= vv.x & vv.y & vv.z & vv.w;
    }
    if (acc == 0) atomicAnd(flag, 0);
  }
}

// ---------------------------------------------------------------- merged QKV projection
__global__ __launch_bounds__(256) void proj_qkv(
    const unsigned short* __restrict__ Abase, const unsigned short* __restrict__ Wbase,
    const float* __restrict__ b_q, const float* __restrict__ b_k,
    const float* __restrict__ b_v, unsigned short* __restrict__ qhf,
    unsigned short* __restrict__ khf, unsigned short* __restrict__ vhf,
    float qscale) {
  const int z = blockIdx.z;
  const unsigned short* Af = Abase + (size_t)z * A_ELEMS;
  const unsigned short* Wf = Wbase + (size_t)z * W_ELEMS;
  const float* bias = (z == 0) ? b_q : (z == 1) ? b_k : b_v;
  unsigned short* outp = (z == 0) ? qhf : (z == 1) ? khf : vhf;
  const float scale = (z == 0) ? qscale : 1.0f;

  const int t = threadIdx.x, l = t & 63, w = t >> 6;
  const int wr = w >> 1, wc = w & 1;
  const int bx = blockIdx.x, by = blockIdx.y;

  const unsigned short* a0 = Af + (((size_t)(bx * 8 + wr * 4) * 32) << 9) + l * 8;
  const unsigned short* b0 = Wf + (((size_t)(by * 4 + wc * 2) * 32) << 9) + l * 8;

  f32x4 acc[4][2];
#pragma unroll
  for (int m = 0; m < 4; ++m)
#pragma unroll
    for (int n = 0; n < 2; ++n) acc[m][n] = {0.f, 0.f, 0.f, 0.f};

#pragma unroll 4
  for (int c = 0; c < 32; ++c) {
    bf16x8 af[4], bfr[2];
#pragma unroll
    for (int m = 0; m < 4; ++m)
      af[m] = *(const bf16x8*)(a0 + (((size_t)(m * 32 + c)) << 9));
#pragma unroll
    for (int n = 0; n < 2; ++n)
      bfr[n] = *(const bf16x8*)(b0 + (((size_t)(n * 32 + c)) << 9));
#pragma unroll
    for (int n = 0; n < 2; ++n)
#pragma unroll
      for (int m = 0; m < 4; ++m)
        acc[m][n] = __builtin_amdgcn_mfma_f32_16x16x32_bf16(af[m], bfr[n], acc[m][n], 0, 0, 0);
  }

  const int l4 = (l >> 4) << 2, cl = l & 15;
#pragma unroll
  for (int n = 0; n < 2; ++n) {
    const int gc = by * 64 + wc * 32 + n * 16 + cl;
    const float bi = bias[gc];
#pragma unroll
    for (int m = 0; m < 4; ++m) {
      const int gr0 = bx * 128 + wr * 64 + m * 16 + l4;
      const int b = gr0 >> 11, s0 = gr0 & 2047, h = gc >> 6, d = gc & 63;
      const size_t base = (size_t)(b * 16 + h) * BH_ELEMS;
      if (z != 2) {
#pragma unroll
        for (int j = 0; j < 4; ++j) {
          const int s = s0 + j;
          size_t addr = base + ((size_t)((s >> 4) * 2 + (d >> 5)) << 9) +
                        (((d >> 3) & 3) << 7) + ((s & 15) << 3) + (d & 7);
          outp[addr] = f2bf((acc[m][n][j] + bi) * scale);
        }
      } else {
        size_t addr = base + ((size_t)((s0 >> 5) * 4 + (d >> 4)) << 9) +
                      (((s0 >> 3) & 3) << 7) + ((d & 15) << 3) + (s0 & 7);
        u16x4 pk;
#pragma unroll
        for (int j = 0; j < 4; ++j) pk[j] = f2bf(acc[m][n][j] + bi);
        *(u16x4*)(outp + addr) = pk;
      }
    }
  }
}

// ---------------------------------------------------------------- O projection
__global__ __launch_bounds__(256) void proj_o(const unsigned short* __restrict__ Af,
                                              const unsigned short* __restrict__ Wf,
                                              const float* __restrict__ bias,
                                              float* __restrict__ outp) {
  const int t = threadIdx.x, l = t & 63, w = t >> 6;
  const int wr = w >> 1, wc = w & 1;
  const int bx = blockIdx.x, by = blockIdx.y;

  const unsigned short* a0 = Af + (((size_t)(bx * 8 + wr * 4) * 32) << 9) + l * 8;
  const unsigned short* b0 = Wf + (((size_t)(by * 4 + wc * 2) * 32) << 9) + l * 8;

  f32x4 acc[4][2];
#pragma unroll
  for (int m = 0; m < 4; ++m)
#pragma unroll
    for (int n = 0; n < 2; ++n) acc[m][n] = {0.f, 0.f, 0.f, 0.f};

#pragma unroll 4
  for (int c = 0; c < 32; ++c) {
    bf16x8 af[4], bfr[2];
#pragma unroll
    for (int m = 0; m < 4; ++m)
      af[m] = *(const bf16x8*)(a0 + (((size_t)(m * 32 + c)) << 9));
#pragma unroll
    for (int n = 0; n < 2; ++n)
      bfr[n] = *(const bf16x8*)(b0 + (((size_t)(n * 32 + c)) << 9));
#pragma unroll
    for (int n = 0; n < 2; ++n)
#pragma unroll
      for (int m = 0; m < 4; ++m)
        acc[m][n] = __builtin_amdgcn_mfma_f32_16x16x32_bf16(af[m], bfr[n], acc[m][n], 0, 0, 0);
  }

  const int l4 = (l >> 4) << 2, cl = l & 15;
#pragma unroll
  for (int n = 0; n < 2; ++n) {
    const int gc = by * 64 + wc * 32 + n * 16 + cl;
    const float bi = bias[gc];
#pragma unroll
    for (int m = 0; m < 4; ++m) {
      const int gr0 = bx * 128 + wr * 64 + m * 16 + l4;
#pragma unroll
      for (int j = 0; j < 4; ++j)
        outp[(size_t)(gr0 + j) * 1024 + gc] = acc[m][n][j] + bi;
    }
  }
}

// ---------------------------------------------------------------- attention v4 (measured best)
// One block = one (b,h) x 16 query rows. 512 thr / 8 waves.
// Wave w owns contiguous k-range [w*256, w*256+256). Swapped QK^T: lane l
// owns row q = l&15, k = w*256 + ct*16 + 4*(l>>4) + j.
__global__ __launch_bounds__(512, 4) void attn_v4(const unsigned short* __restrict__ Qf,
                                                  const unsigned short* __restrict__ Kf,
                                                  const unsigned short* __restrict__ Vf,
                                                  const int* __restrict__ mask,
                                                  const int* __restrict__ flag,
                                                  float* __restrict__ Pout,
                                                  unsigned short* __restrict__ ctxf) {
  __shared__ float red[8 * 1024];   // 32 KB ctx cross-wave reduce
  __shared__ float rred[8][16];

  const int t = threadIdx.x, l = t & 63, w = t >> 6;
  const int bid = blockIdx.x;
  const int swz = (bid & 7) * 512 + (bid >> 3);   // bijective: 4096 % 8 == 0
  const int bh = swz >> 7, rt = swz & 127;
  const int q0 = rt * 16;
  const int g = l >> 4, q = l & 15;

  const unsigned short* qf = Qf + (size_t)bh * BH_ELEMS + l * 8;
  const unsigned short* kf = Kf + (size_t)bh * BH_ELEMS + l * 8;
  const unsigned short* vf = Vf + (size_t)bh * BH_ELEMS + l * 8;

  const bf16x8 aq0 = *(const bf16x8*)(qf + ((size_t)(rt * 2) << 9));
  const bf16x8 aq1 = *(const bf16x8*)(qf + ((size_t)(rt * 2 + 1) << 9));

  // ---- scores (swapped: A=K rows=k, B=Q cols=q)
  f32x4 sacc[16];
#pragma unroll
  for (int ct = 0; ct < 16; ++ct) {
    const int gi = w * 16 + ct;
    bf16x8 ak0 = *(const bf16x8*)(kf + ((size_t)(gi * 2) << 9));
    bf16x8 ak1 = *(const bf16x8*)(kf + ((size_t)(gi * 2 + 1) << 9));
    f32x4 s = {0.f, 0.f, 0.f, 0.f};
    s = __builtin_amdgcn_mfma_f32_16x16x32_bf16(ak0, aq0, s, 0, 0, 0);
    s = __builtin_amdgcn_mfma_f32_16x16x32_bf16(ak1, aq1, s, 0, 0, 0);
    sacc[ct] = s;
    if ((ct & 3) == 3) __builtin_amdgcn_sched_barrier(0);
  }

  // ---- mask slow path
  if (*flag == 0) {
#pragma unroll
    for (int ct = 0; ct < 16; ++ct) {
      const int col = w * 256 + ct * 16 + g * 4;
#pragma unroll
      for (int j = 0; j < 4; ++j)
        if (mask[(size_t)(q0 + q) * S + col + j] == 0) sacc[ct][j] = -1e9f;
    }
  }

  // ---- softmax over the lane's single row (scores pre-scaled by log2e)
  float m = -1e30f;
#pragma unroll
  for (int ct = 0; ct < 16; ++ct)
#pragma unroll
    for (int j = 0; j < 4; ++j) m = fmaxf(m, sacc[ct][j]);
  m = fmaxf(m, __shfl_xor(m, 16));
  m = fmaxf(m, __shfl_xor(m, 32));
  if (l < 16) rred[w][l] = m;
  __syncthreads();
  float mm = rred[0][q];
#pragma unroll
  for (int ww = 1; ww < 8; ++ww) mm = fmaxf(mm, rred[ww][q]);
  __syncthreads();

  float z = 0.f;
#pragma unroll
  for (int ct = 0; ct < 16; ++ct)
#pragma unroll
    for (int j = 0; j < 4; ++j) {
      float p = exp2f(sacc[ct][j] - mm);
      sacc[ct][j] = p;
      z += p;
    }
  z += __shfl_xor(z, 16);
  z += __shfl_xor(z, 32);
  if (l < 16) rred[w][l] = z;
  __syncthreads();
  float zz = rred[0][q];
#pragma unroll
  for (int ww = 1; ww < 8; ++ww) zz += rred[ww][q];
  const float inv = 1.0f / zz;

  // ---- normalize + vectorized nontemporal P store (row-contiguous)
  float* prow = Pout + ((size_t)bh * S + q0 + q) * S + w * 256 + g * 4;
#pragma unroll
  for (int ct = 0; ct < 16; ++ct) {
    f32x4 pn = sacc[ct] * inv;
    sacc[ct] = pn;
    __builtin_nontemporal_store(pn, (f32x4*)(prow + ct * 16));
  }

  // ---- pack ALL P -> bf16 A-frags in-register (butterfly); sacc dies here
  u32x4 pa[8];
#pragma unroll
  for (int ks = 0; ks < 8; ++ks) {
    const int t0 = ks * 2, t1 = t0 + 1;
    unsigned Xa, Xb, Ya, Yb;
    asm("v_cvt_pk_bf16_f32 %0, %1, %2" : "=v"(Xa) : "v"(sacc[t0][0]), "v"(sacc[t0][1]));
    asm("v_cvt_pk_bf16_f32 %0, %1, %2" : "=v"(Xb) : "v"(sacc[t0][2]), "v"(sacc[t0][3]));
    asm("v_cvt_pk_bf16_f32 %0, %1, %2" : "=v"(Ya) : "v"(sacc[t1][0]), "v"(sacc[t1][1]));
    asm("v_cvt_pk_bf16_f32 %0, %1, %2" : "=v"(Yb) : "v"(sacc[t1][2]), "v"(sacc[t1][3]));
    const bool lo2 = (g < 2);
    unsigned sel_a = lo2 ? Ya : Xa, sel_b = lo2 ? Yb : Xb;
    unsigned kept_a = lo2 ? Xa : Ya, kept_b = lo2 ? Xb : Yb;
    unsigned r1_a = (unsigned)__shfl_xor((int)sel_a, 32);
    unsigned r1_b = (unsigned)__shfl_xor((int)sel_b, 32);
    const bool mid = (g == 1) || (g == 2);
    unsigned s2_a = mid ? kept_a : r1_a;
    unsigned s2_b = mid ? kept_b : r1_b;
    unsigned r2_a = (unsigned)__shfl_xor((int)s2_a, 16);
    unsigned r2_b = (unsigned)__shfl_xor((int)s2_b, 16);
    u32x4 fr;
    fr[0] = (g == 0) ? kept_a : ((g == 2) ? r1_a : r2_a);
    fr[1] = (g == 0) ? kept_b : ((g == 2) ? r1_b : r2_b);
    fr[2] = (g == 3) ? kept_a : ((g == 1) ? r1_a : r2_a);
    fr[3] = (g == 3) ? kept_b : ((g == 1) ? r1_b : r2_b);
    pa[ks] = fr;
  }

  // ---- PV: pure MFMA stream (V-frag loads free to hoist into pack phase)
  f32x4 pacc[4];
#pragma unroll
  for (int n = 0; n < 4; ++n) pacc[n] = {0.f, 0.f, 0.f, 0.f};

  __builtin_amdgcn_s_setprio(1);
#pragma unroll
  for (int ks = 0; ks < 8; ++ks) {
    const bf16x8 ap = __builtin_bit_cast(bf16x8, pa[ks]);
    const int kbi = w * 8 + ks;
#pragma unroll
    for (int n = 0; n < 4; ++n) {
      bf16x8 bv = *(const bf16x8*)(vf + ((size_t)(kbi * 4 + n) << 9));
      pacc[n] = __builtin_amdgcn_mfma_f32_16x16x32_bf16(ap, bv, pacc[n], 0, 0, 0);
    }
  }
  __builtin_amdgcn_s_setprio(0);

  // ---- cross-wave K-slice reduce (f32 [8][1024]) -> ctx A-frag out
#pragma unroll
  for (int n = 0; n < 4; ++n)
#pragma unroll
    for (int j = 0; j < 4; ++j)
      red[w * 1024 + (g * 4 + j) * 64 + n * 16 + q] = pacc[n][j];
  __syncthreads();
  const int b = bh >> 4, h = bh & 15;
#pragma unroll
  for (int i = 0; i < 2; ++i) {
    int idx = t * 2 + i;
    float s = red[idx];
#pragma unroll
    for (int ww = 1; ww < 8; ++ww) s += red[ww * 1024 + idx];
    int qrow = idx >> 6, d = idx & 63;
    size_t addr = ((size_t)((b * 128 + rt) * 32 + h * 2 + (d >> 5)) << 9) +
                  (((d >> 3) & 3) << 7) + (qrow << 3) + (d & 7);
    ctxf[addr] = f2bf(s);
  }
}

// ---------------------------------------------------------------- launch
extern "C" void kernel_launch(void* const* d_in, const int* in_sizes, int n_in,
                              void* d_out, int out_size, void* d_ws, size_t ws_size,
                              hipStream_t stream) {
  const float* q = (const float*)d_in[0];
  const float* k = (const float*)d_in[1];
  const float* v = (const float*)d_in[2];
  const int* mask = (const int*)d_in[3];
  const float* w_q = (const float*)d_in[4];
  const float* b_q = (const float*)d_in[5];
  const float* w_k = (const float*)d_in[6];
  const float* b_k = (const float*)d_in[7];
  const float* w_v = (const float*)d_in[8];
  const float* b_v = (const float*)d_in[9];
  const float* w_o = (const float*)d_in[10];
  const float* b_o = (const float*)d_in[11];

  unsigned short* wsu = (unsigned short*)d_ws;
  unsigned short* A0 = wsu + 0 * A_ELEMS;  // qbf -> ctxf
  unsigned short* Wb = wsu + 4 * A_ELEMS;  // wqf|wkf|wvf|wof
  unsigned short* A3 = wsu + 3 * A_ELEMS;  // qhf
  unsigned short* wof = Wb + 3 * W_ELEMS;
  int* flag = (int*)(Wb + 4 * W_ELEMS);

  float* out_f = (float*)d_out;                  // [4096][1024] f32
  float* attnW = out_f + (size_t)4096 * 1024;    // [2][16][2048][2048] f32
  // khf/vhf scratch inside the (not-yet-final) `out` region:
  unsigned short* khf = (unsigned short*)d_out;          // 8.39 MB
  unsigned short* vhf = khf + A_ELEMS;                   // 8.39 MB

  (void)hipMemsetAsync(flag, 0xFF, 4, stream);  // flag!=0 default; mask ANDs to 0
  prologue_kernel<<<9216, 256, 0, stream>>>(q, k, v, w_q, w_k, w_v, w_o, mask,
                                            A0, Wb, flag);

  // qscale folds 1/sqrt(64) AND log2(e) (softmax done in exp2 domain).
  const float qscale = 0.125f * 1.4426950408889634f;
  proj_qkv<<<dim3(32, 16, 3), 256, 0, stream>>>(A0, Wb, b_q, b_k, b_v,
                                                A3, khf, vhf, qscale);

  attn_v4<<<4096, 512, 0, stream>>>(A3, khf, vhf, mask, flag, attnW, A0);

  proj_o<<<dim3(32, 16), 256, 0, stream>>>(A0, wof, b_o, out_f);
}